// Round 4
// baseline (11617.538 us; speedup 1.0000x reference)
//
#include <hip/hip_runtime.h>
#include <hip/hip_cooperative_groups.h>
#include <math.h>

namespace cg = cooperative_groups;

#define Bsz 512
#define Nn  24
#define Tt  25
// layer1 per-step K=192 ([loc,locd 8 | h1 128 | pad]), z-part hoisted into base1
// layer2 K=256 ([h1|h2]); fc K=128; init K=256(enc); base1 K=64(z)

typedef _Float16 f16;
typedef _Float16 f16x8 __attribute__((ext_vector_type(8)));
typedef _Float16 f16x4 __attribute__((ext_vector_type(4)));
typedef float f32x4 __attribute__((ext_vector_type(4)));

// ===========================================================================
// Phase device functions. All share one 28 KB static LDS block (reinterpreted
// per phase). Every phase body is one "virtual block"; caller loops vb and
// grid-syncs between phases.
// ===========================================================================

// ---- generic MFMA gemm tile: 64 o-rows x 128 b-cols, FM=2 FN=4 -------------
__device__ __forceinline__ void gemm_phase(char* smem, int vb,
    const f16* __restrict__ Act, const float* __restrict__ Act32, int Ka,
    const f16* __restrict__ W, size_t wstride,
    const float* __restrict__ bias, int bstride,
    const f16* __restrict__ base16, f16* __restrict__ Y, int O)
{
    f16 (*sW)[72] = (f16(*)[72])smem;                    // 64 x 72 halves
    f16 (*sB)[72] = (f16(*)[72])(smem + 64 * 72 * 2);    // 128 x 72 halves
    const int nox = O >> 6;
    const int n   = vb % Nn;
    const int rem = vb / Nn;
    const int o0  = (rem % nox) * 64;
    const int b0  = (rem / nox) * 128;
    const int tid = threadIdx.x;
    const int wave = tid >> 6, lane = tid & 63;
    const int wm = (wave >> 1) * 32;   // wave o offset
    const int wn = (wave & 1) * 64;    // wave b offset
    const int m16 = lane & 15, quad = lane >> 4;
    const f16* Wn = W + (size_t)n * wstride;
    f32x4 acc[2][4] = {};
    const int r = tid >> 3, cc = (tid & 7) * 8;

    for (int k0 = 0; k0 < Ka; k0 += 64) {
        for (int row = r; row < 64; row += 32)
            *(f16x8*)&sW[row][cc] = *(const f16x8*)&Wn[(size_t)(o0 + row) * Ka + k0 + cc];
        if (Act) {
            for (int row = r; row < 128; row += 32)
                *(f16x8*)&sB[row][cc] = *(const f16x8*)&Act[((size_t)(b0 + row) * Nn + n) * Ka + k0 + cc];
        } else {
            for (int row = r; row < 128; row += 32) {
                const float* src = &Act32[((size_t)(b0 + row) * Nn + n) * Ka + k0 + cc];
                f16x8 v;
#pragma unroll
                for (int u = 0; u < 8; u++) v[u] = (f16)src[u];
                *(f16x8*)&sB[row][cc] = v;
            }
        }
        __syncthreads();
#pragma unroll
        for (int kk = 0; kk < 64; kk += 32) {
            f16x8 af[2], bf[4];
#pragma unroll
            for (int i = 0; i < 2; i++)
                af[i] = *(const f16x8*)&sW[wm + i * 16 + m16][kk + quad * 8];
#pragma unroll
            for (int j = 0; j < 4; j++)
                bf[j] = *(const f16x8*)&sB[wn + j * 16 + m16][kk + quad * 8];
#pragma unroll
            for (int i = 0; i < 2; i++)
#pragma unroll
                for (int j = 0; j < 4; j++)
                    acc[i][j] = __builtin_amdgcn_mfma_f32_16x16x32_f16(af[i], bf[j], acc[i][j], 0, 0, 0);
        }
        __syncthreads();
    }
#pragma unroll
    for (int i = 0; i < 2; i++) {
        const int orow = o0 + wm + i * 16 + quad * 4;
        float4 bv = make_float4(0.f, 0.f, 0.f, 0.f);
        if (bias) bv = *(const float4*)&bias[(size_t)n * bstride + orow];
#pragma unroll
        for (int j = 0; j < 4; j++) {
            const int bcol = b0 + wn + j * 16 + m16;
            size_t yi = ((size_t)bcol * Nn + n) * (size_t)O + orow;
            float v0 = acc[i][j][0] + bv.x;
            float v1 = acc[i][j][1] + bv.y;
            float v2 = acc[i][j][2] + bv.z;
            float v3 = acc[i][j][3] + bv.w;
            if (base16) {
                f16x4 bb = *(const f16x4*)&base16[yi];
                v0 += (float)bb[0]; v1 += (float)bb[1];
                v2 += (float)bb[2]; v3 += (float)bb[3];
            }
            f16x4 o4; o4[0] = (f16)v0; o4[1] = (f16)v1; o4[2] = (f16)v2; o4[3] = (f16)v3;
            *(f16x4*)&Y[yi] = o4;
        }
    }
}

// ---- G-mix + LSTM pointwise, one vb per batch element ----------------------
__device__ __forceinline__ void mixlstm_phase(char* smem, int b,
    const f16* __restrict__ Ypre, const float* __restrict__ Gm,
    float* __restrict__ c, f16* __restrict__ dstA, int strideA,
    f16* __restrict__ dstB, int strideB, int tanhB)
{
    f16* sY   = (f16*)smem;                 // 24 x 512 halves = 24576 B
    float* sG = (float*)(smem + 24576);     // 576 floats
    const int tid = threadIdx.x;
    for (int i = tid; i < 576; i += 256) sG[i] = Gm[i];
    const f16* src = Ypre + (size_t)b * (Nn * 512);
    for (int i = tid; i < 1536; i += 256)
        *(f16x8*)&sY[i * 8] = *(const f16x8*)&src[i * 8];
    __syncthreads();
    for (int w = tid; w < 768; w += 256) {
        const int m = w >> 5, j4 = (w & 31) * 4;
        float gi[4] = {}, gf[4] = {}, gg[4] = {}, go[4] = {};
        const float* gr = &sG[m * 24];
#pragma unroll
        for (int n = 0; n < 24; n++) {
            float g = gr[n];
            const f16* yn = &sY[n * 512];
            f16x4 vi = *(const f16x4*)&yn[j4];
            f16x4 vf = *(const f16x4*)&yn[128 + j4];
            f16x4 vg = *(const f16x4*)&yn[256 + j4];
            f16x4 vo = *(const f16x4*)&yn[384 + j4];
#pragma unroll
            for (int u = 0; u < 4; u++) {
                gi[u] += g * (float)vi[u];
                gf[u] += g * (float)vf[u];
                gg[u] += g * (float)vg[u];
                go[u] += g * (float)vo[u];
            }
        }
        const size_t row = (size_t)b * Nn + m;
        float cv[4];
        *(float4*)cv = *(const float4*)&c[row * 128 + j4];
        f16x4 ha, hb;
#pragma unroll
        for (int u = 0; u < 4; u++) {
            float si = 1.f / (1.f + expf(-gi[u]));
            float sf = 1.f / (1.f + expf(-gf[u]));
            float so = 1.f / (1.f + expf(-go[u]));
            float cn = sf * cv[u] + si * tanhf(gg[u]);
            cv[u] = cn;
            float h = so * tanhf(cn);
            ha[u] = (f16)h;
            hb[u] = (f16)(tanhB ? tanhf(h) : h);
        }
        *(float4*)&c[row * 128 + j4] = *(float4*)cv;
        *(f16x4*)&dstA[row * strideA + j4] = ha;
        *(f16x4*)&dstB[row * strideB + j4] = hb;
    }
    __syncthreads();
}

// ---- init mix: h0/c0 broadcast into states ---------------------------------
__device__ __forceinline__ void mix_init_phase(char* smem, int b,
    const f16* __restrict__ Yhc, const float* __restrict__ Gm,
    f16* __restrict__ xi2, f16* __restrict__ l2cat,
    float* __restrict__ c1, float* __restrict__ c2)
{
    f16* sY   = (f16*)smem;                 // 24 x 256 halves = 12288 B
    float* sG = (float*)(smem + 24576);
    const int tid = threadIdx.x;
    for (int i = tid; i < 576; i += 256) sG[i] = Gm[i];
    const f16* src = Yhc + (size_t)b * (Nn * 256);
    for (int i = tid; i < 768; i += 256)
        *(f16x8*)&sY[i * 8] = *(const f16x8*)&src[i * 8];
    __syncthreads();
    for (int w = tid; w < 768; w += 256) {
        const int m = w >> 5, o4 = (w & 31) * 4;
        float ah[4] = {}, ac[4] = {};
        const float* gr = &sG[m * 24];
#pragma unroll
        for (int n = 0; n < 24; n++) {
            float g = gr[n];
            f16x4 vh = *(const f16x4*)&sY[n * 256 + o4];
            f16x4 vc = *(const f16x4*)&sY[n * 256 + 128 + o4];
#pragma unroll
            for (int u = 0; u < 4; u++) { ah[u] += g * (float)vh[u]; ac[u] += g * (float)vc[u]; }
        }
        const size_t row = (size_t)b * Nn + m;
        f16x4 hf;
#pragma unroll
        for (int u = 0; u < 4; u++) hf[u] = (f16)ah[u];
        *(f16x4*)&xi2[row * 192 + 8 + o4] = hf;
        *(f16x4*)&l2cat[row * 256 + o4] = hf;
        *(f16x4*)&l2cat[row * 256 + 128 + o4] = hf;
        *(float4*)&c1[row * 128 + o4] = *(float4*)ac;
        *(float4*)&c2[row * 128 + o4] = *(float4*)ac;
    }
    __syncthreads();
}

// ---- finstep: fc-mix + tanh, heads, second mix, quaternion, outputs --------
__device__ __forceinline__ void finstep_phase(char* smem, int b,
    const f16* __restrict__ p, const float* __restrict__ Gm,
    const float* __restrict__ locW, const float* __restrict__ locb,
    const float* __restrict__ lzW, const float* __restrict__ lzb,
    float* __restrict__ ls, f16* __restrict__ xi2,
    float* __restrict__ out, int t)
{
    f16* sP   = (f16*)smem;          // 6144 halves
    f16* sY1  = sP + 6144;           // 3072
    f16* sY2  = sY1 + 3072;          // 3072
    float* sG = (float*)(smem + 24576);            // 576 floats (ends 27180)
    float* sSmall = (float*)(smem + 26944);        // 336 floats small arrays
    float (*sLp)[3] = (float(*)[3])sSmall;         // 72
    float (*sZp)[4] = (float(*)[4])(sSmall + 72);  // 96
    float (*sL3)[3] = (float(*)[3])(sSmall + 168); // 72
    float (*sZ3)[4] = (float(*)[4])(sSmall + 240); // 96
    const int tid = threadIdx.x;
    for (int i = tid; i < 576; i += 256) sG[i] = Gm[i];
    const f16* src = p + (size_t)b * (Nn * 256);
    for (int i = tid; i < 768; i += 256)
        *(f16x8*)&sP[i * 8] = *(const f16x8*)&src[i * 8];
    __syncthreads();
    for (int w = tid; w < 768; w += 256) {
        const int m = w >> 5, o4 = (w & 31) * 4;
        float a1[4] = {}, a2[4] = {};
        const float* gr = &sG[m * 24];
#pragma unroll
        for (int n = 0; n < 24; n++) {
            float g = gr[n];
            f16x4 p1 = *(const f16x4*)&sP[n * 256 + o4];
            f16x4 p2 = *(const f16x4*)&sP[n * 256 + 128 + o4];
#pragma unroll
            for (int u = 0; u < 4; u++) { a1[u] += g * (float)p1[u]; a2[u] += g * (float)p2[u]; }
        }
        f16x4 y1, y2;
#pragma unroll
        for (int u = 0; u < 4; u++) { y1[u] = (f16)tanhf(a1[u]); y2[u] = (f16)tanhf(a2[u]); }
        *(f16x4*)&sY1[m * 128 + o4] = y1;
        *(f16x4*)&sY2[m * 128 + o4] = y2;
    }
    __syncthreads();
    if (tid < 72) {
        int m = tid / 3, j = tid - m * 3;
        float s = locb[j];
        for (int o = 0; o < 128; o++) s += (float)sY1[m * 128 + o] * locW[o * 3 + j];
        sLp[m][j] = s;
    } else if (tid < 168) {
        int w2 = tid - 72; int m = w2 >> 2, j = w2 & 3;
        float s = lzb[j];
        for (int o = 0; o < 128; o++) s += (float)sY2[m * 128 + o] * lzW[o * 4 + j];
        sZp[m][j] = s;
    }
    __syncthreads();
    if (tid < 72) {
        int m = tid / 3, j = tid - m * 3;
        float s = 0.f;
#pragma unroll
        for (int n = 0; n < 24; n++) s += sG[m * 24 + n] * sLp[n][j];
        sL3[m][j] = s;
    } else if (tid < 168) {
        int w2 = tid - 72; int m = w2 >> 2, j = w2 & 3;
        float s = 0.f;
#pragma unroll
        for (int n = 0; n < 24; n++) s += sG[m * 24 + n] * sZp[n][j];
        sZ3[m][j] = s;
    }
    __syncthreads();
    if (tid < 24) {
        const int m = tid;
        float xx = sL3[m][0], xy = sL3[m][1], xz = sL3[m][2];
        float r = rsqrtf(1.f + xx * xx + xy * xy + xz * xz);
        float dw = r, dx = xx * r, dy = xy * r, dz = xz * r;
        size_t li = ((size_t)b * Nn + m) * 4;
        float qw = ls[li], qx = ls[li + 1], qy = ls[li + 2], qz = ls[li + 3];
        float lw = qw * dw - qx * dx - qy * dy - qz * dz;
        float lx = qw * dx + qx * dw + qy * dz - qz * dy;
        float ly = qw * dy - qx * dz + qy * dw + qz * dx;
        float lz = qw * dz + qx * dy - qy * dx + qz * dw;
        size_t oi = (((size_t)b * Tt + t) * Nn + m) * 4;
        out[oi + 0] = lw; out[oi + 1] = lx; out[oi + 2] = ly; out[oi + 3] = lz;
        size_t zi = (size_t)Bsz * Tt * Nn * 4 + oi;
        out[zi + 0] = sZ3[m][0]; out[zi + 1] = sZ3[m][1];
        out[zi + 2] = sZ3[m][2]; out[zi + 3] = sZ3[m][3];
        ls[li] = lw; ls[li + 1] = lx; ls[li + 2] = ly; ls[li + 3] = lz;
        size_t xb = ((size_t)b * Nn + m) * 192;
        xi2[xb + 0] = (f16)lw; xi2[xb + 1] = (f16)lx; xi2[xb + 2] = (f16)ly; xi2[xb + 3] = (f16)lz;
        xi2[xb + 4] = (f16)dw; xi2[xb + 5] = (f16)dx; xi2[xb + 6] = (f16)dy; xi2[xb + 7] = (f16)dz;
    }
    __syncthreads();
}

// ===========================================================================
// The persistent cooperative kernel: whole scan in one dispatch.
// ===========================================================================
struct DecParams {
    const float *z, *enc, *G;
    const float *bias0, *bias1, *bi, *bcat;
    const float *locW, *locb, *lzW, *lzb;
    const f16 *Wz, *Wt0, *Wt1, *Wtf, *Wti;
    f16 *base1, *xi2, *l2cat, *yib, *yp, *pbuf;
    float *c1, *c2, *ls, *out;
};

__global__ __launch_bounds__(256, 3) void decoder_loop(DecParams p)
{
    cg::grid_group grid = cg::this_grid();
    __shared__ __attribute__((aligned(16))) char smem[28672];
    const int nb = gridDim.x, bid = blockIdx.x;

    // phase 0: base1 = z.Wz + b0 (768 vb) ; [h0|c0]pre = enc.Wti + bi (384 vb)
    for (int vb = bid; vb < 1152; vb += nb) {
        if (vb < 768)
            gemm_phase(smem, vb, nullptr, p.z, 64, p.Wz, (size_t)512 * 64,
                       p.bias0, 512, nullptr, p.base1, 512);
        else
            gemm_phase(smem, vb - 768, nullptr, p.enc, 256, p.Wti, 0,
                       p.bi, 0, nullptr, p.yp, 256);
    }
    grid.sync();
    for (int vb = bid; vb < Bsz; vb += nb)
        mix_init_phase(smem, vb, p.yp, p.G, p.xi2, p.l2cat, p.c1, p.c2);
    grid.sync();

    for (int t = 0; t < Tt; t++) {
        for (int vb = bid; vb < 768; vb += nb)
            gemm_phase(smem, vb, p.xi2, nullptr, 192, p.Wt0, (size_t)512 * 192,
                       nullptr, 0, p.base1, p.yp, 512);
        grid.sync();
        for (int vb = bid; vb < Bsz; vb += nb)
            mixlstm_phase(smem, vb, p.yp, p.G, p.c1, p.xi2 + 8, 192, p.l2cat, 256, 0);
        grid.sync();
        for (int vb = bid; vb < 768; vb += nb)
            gemm_phase(smem, vb, p.l2cat, nullptr, 256, p.Wt1, (size_t)512 * 256,
                       p.bias1, 512, nullptr, p.yp, 512);
        grid.sync();
        for (int vb = bid; vb < Bsz; vb += nb)
            mixlstm_phase(smem, vb, p.yp, p.G, p.c2, p.l2cat + 128, 256, p.yib, 128, 1);
        grid.sync();
        for (int vb = bid; vb < 384; vb += nb)
            gemm_phase(smem, vb, p.yib, nullptr, 128, p.Wtf, (size_t)256 * 128,
                       p.bcat, 256, nullptr, p.pbuf, 256);
        grid.sync();
        for (int vb = bid; vb < Bsz; vb += nb)
            finstep_phase(smem, vb, p.pbuf, p.G, p.locW, p.locb, p.lzW, p.lzb,
                          p.ls, p.xi2, p.out, t);
        grid.sync();
    }
}

// ===========================================================================
// One-time prep kernels (normal launches, outside the hot loop)
// ===========================================================================
__global__ __launch_bounds__(256) void prep_w01(
    const float* __restrict__ Wx0, const float* __restrict__ Wh0,
    const float* __restrict__ Wx1, const float* __restrict__ Wh1,
    f16* __restrict__ Wz, f16* __restrict__ Wt0, f16* __restrict__ Wt1)
{
    size_t idx = (size_t)blockIdx.x * 256 + threadIdx.x;
    const size_t nz = (size_t)Nn * 512 * 64;
    const size_t n0 = (size_t)Nn * 512 * 192;
    const size_t n1 = (size_t)Nn * 512 * 256;
    if (idx < nz) {
        int k = idx & 63; int o = (idx >> 6) & 511; int n = (int)(idx >> 15);
        Wz[idx] = (f16)Wx0[((size_t)n * 72 + k) * 512 + o];
    } else if (idx < nz + n0) {
        size_t i2 = idx - nz;
        int k = (int)(i2 % 192);
        size_t no = i2 / 192;
        int o = (int)(no & 511); int n = (int)(no >> 9);
        float v = 0.f;
        if (k < 8) v = Wx0[((size_t)n * 72 + 64 + k) * 512 + o];
        else if (k < 136) v = Wh0[((size_t)n * 128 + (k - 8)) * 512 + o];
        Wt0[i2] = (f16)v;
    } else if (idx < nz + n0 + n1) {
        size_t i3 = idx - nz - n0;
        int k = (int)(i3 & 255);
        size_t no = i3 >> 8;
        int o = (int)(no & 511); int n = (int)(no >> 9);
        float v = (k < 128) ? Wx1[((size_t)n * 128 + k) * 512 + o]
                            : Wh1[((size_t)n * 128 + (k - 128)) * 512 + o];
        Wt1[i3] = (f16)v;
    }
}

__global__ __launch_bounds__(256) void prep_wf(
    const float* __restrict__ fcW, const float* __restrict__ fc2W,
    f16* __restrict__ Wtf)
{
    size_t idx = (size_t)blockIdx.x * 256 + threadIdx.x;
    if (idx >= (size_t)Nn * 256 * 128) return;
    int k = (int)(idx & 127);
    size_t no = idx >> 7;
    int o = (int)(no & 255); int n = (int)(no >> 8);
    float v = (o < 128) ? fcW[((size_t)n * 128 + k) * 128 + o]
                        : fc2W[((size_t)n * 128 + k) * 128 + (o - 128)];
    Wtf[idx] = (f16)v;
}

__global__ __launch_bounds__(256) void prep_wi(
    const float* __restrict__ ih1W, const float* __restrict__ ih2W,
    const float* __restrict__ ih1b, const float* __restrict__ ih2b,
    const float* __restrict__ fcb, const float* __restrict__ fc2b,
    f16* __restrict__ Wti, float* __restrict__ bi, float* __restrict__ bcat)
{
    int idx = blockIdx.x * 256 + threadIdx.x;
    int k = idx & 255, o = idx >> 8;
    Wti[idx] = (f16)((o < 128) ? ih1W[(size_t)k * 128 + o] : ih2W[(size_t)k * 128 + (o - 128)]);
    if (idx < 256) bi[idx] = (idx < 128) ? ih1b[idx] : ih2b[idx - 128];
    if (idx < Nn * 256) {
        int n = idx >> 8, oo = idx & 255;
        bcat[idx] = (oo < 128) ? fcb[n * 128 + oo] : fc2b[n * 128 + (oo - 128)];
    }
}

__global__ __launch_bounds__(256) void init_xi(
    const float* __restrict__ x, f16* __restrict__ xi2, float* __restrict__ ls)
{
    size_t idx = (size_t)blockIdx.x * 256 + threadIdx.x;
    const size_t total = (size_t)Bsz * Nn * 192;
    if (idx < total) {
        size_t bn = idx / 192;
        int k = (int)(idx - bn * 192);
        if (k < 8) xi2[idx] = (f16)x[bn * 8 + k];
        else if (k >= 136) xi2[idx] = (f16)0.f;
    }
    if (idx < (size_t)Bsz * Nn * 4) {
        size_t bn = idx >> 2;
        ls[idx] = x[bn * 8 + (idx & 3)];
    }
}

extern "C" void kernel_launch(void* const* d_in, const int* in_sizes, int n_in,
                              void* d_out, int out_size, void* d_ws, size_t ws_size,
                              hipStream_t stream)
{
    const float* x    = (const float*)d_in[0];
    const float* enc  = (const float*)d_in[1];
    const float* z    = (const float*)d_in[2];
    const float* G    = (const float*)d_in[4];
    const float* Wx0  = (const float*)d_in[5];
    const float* Wh0  = (const float*)d_in[6];
    const float* b0i  = (const float*)d_in[7];
    const float* Wx1  = (const float*)d_in[8];
    const float* Wh1  = (const float*)d_in[9];
    const float* b1i  = (const float*)d_in[10];
    const float* fcW  = (const float*)d_in[11];
    const float* fcb  = (const float*)d_in[12];
    const float* fc2W = (const float*)d_in[13];
    const float* fc2b = (const float*)d_in[14];
    const float* ih1W = (const float*)d_in[15];
    const float* ih1b = (const float*)d_in[16];
    const float* ih2W = (const float*)d_in[17];
    const float* ih2b = (const float*)d_in[18];
    const float* locW = (const float*)d_in[19];
    const float* locb = (const float*)d_in[20];
    const float* lzW  = (const float*)d_in[21];
    const float* lzb  = (const float*)d_in[22];

    const size_t BN = (size_t)Bsz * Nn;
    char* wp = (char*)d_ws;
    size_t off = 0;
    auto carve = [&](size_t bytes) -> char* {
        char* pc = wp + off;
        off += (bytes + 255) & ~(size_t)255;
        return pc;
    };
    f16*   Wz     = (f16*)carve((size_t)Nn * 512 * 64 * 2);
    f16*   Wt0    = (f16*)carve((size_t)Nn * 512 * 192 * 2);
    f16*   Wt1    = (f16*)carve((size_t)Nn * 512 * 256 * 2);
    f16*   Wtf    = (f16*)carve((size_t)Nn * 256 * 128 * 2);
    f16*   Wti    = (f16*)carve((size_t)256 * 256 * 2);
    float* bcat   = (float*)carve((size_t)Nn * 256 * 4);
    float* bi     = (float*)carve(256 * 4);
    f16*   base1  = (f16*)carve(BN * 512 * 2);
    f16*   xi2    = (f16*)carve(BN * 192 * 2);
    f16*   l2cat  = (f16*)carve(BN * 256 * 2);
    f16*   yib    = (f16*)carve(BN * 128 * 2);
    float* c1     = (float*)carve(BN * 128 * 4);
    float* c2     = (float*)carve(BN * 128 * 4);
    float* ls     = (float*)carve(BN * 4 * 4);
    f16*   yp     = (f16*)carve(BN * 512 * 2);
    f16*   pbuf   = (f16*)carve(BN * 256 * 2);

    // ---- one-time prep ----
    prep_w01<<<24576, 256, 0, stream>>>(Wx0, Wh0, Wx1, Wh1, Wz, Wt0, Wt1);
    prep_wf<<<3072, 256, 0, stream>>>(fcW, fc2W, Wtf);
    prep_wi<<<256, 256, 0, stream>>>(ih1W, ih2W, ih1b, ih2b, fcb, fc2b, Wti, bi, bcat);
    init_xi<<<9216, 256, 0, stream>>>(x, xi2, ls);

    // ---- persistent cooperative kernel: init GEMMs + full T-loop ----
    DecParams p;
    p.z = z; p.enc = enc; p.G = G;
    p.bias0 = b0i; p.bias1 = b1i; p.bi = bi; p.bcat = bcat;
    p.locW = locW; p.locb = locb; p.lzW = lzW; p.lzb = lzb;
    p.Wz = Wz; p.Wt0 = Wt0; p.Wt1 = Wt1; p.Wtf = Wtf; p.Wti = Wti;
    p.base1 = base1; p.xi2 = xi2; p.l2cat = l2cat; p.yib = yib;
    p.yp = yp; p.pbuf = pbuf;
    p.c1 = c1; p.c2 = c2; p.ls = ls; p.out = (float*)d_out;

    int maxb = 3;
    (void)hipOccupancyMaxActiveBlocksPerMultiprocessor(&maxb, decoder_loop, 256, 0);
    int nblocks = maxb * 256;
    if (nblocks > 768) nblocks = 768;
    if (nblocks < 256) nblocks = 256;
    void* args[] = { (void*)&p };
    hipLaunchCooperativeKernel((const void*)decoder_loop, dim3(nblocks), dim3(256),
                               args, 0, stream);
}

// Round 5
// 2661.254 us; speedup vs baseline: 4.3654x; 4.3654x over previous
//
#include <hip/hip_runtime.h>
#include <math.h>

#define Bsz 512
#define Nn  24
#define Tt  25
// Step pipeline (5 kernels): mix1 -> gemm2ext -> mix2 -> gemmf -> finstep+
//   gates1(t) [ypA] = h1(t-1)·Wh0 (from gemm2ext(t-1)) + base1(z·Wz+b0) + [loc|locd]·W8 (finstep)
//   gemm2ext(t): l2cat=[h1(t)|h2(t-1)] (K=256) x W2ext (O=1024) = [gates2(t) | partial1(t+1)]
// Cooperative grid.sync was 4.7x slower (L2 invalidation per sync, 18.5GB refetch) - do NOT use.

typedef _Float16 f16;
typedef _Float16 f16x8 __attribute__((ext_vector_type(8)));
typedef _Float16 f16x4 __attribute__((ext_vector_type(4)));
typedef float f32x4 __attribute__((ext_vector_type(4)));

// ---------------------------------------------------------------------------
// MFMA fp16 GEMM, per-node block-diagonal, W-as-A orientation:
//   Y[b,n,o] = sum_k Act[b,n,k] * W[n,o,k] + bias[n,o] (+ base16[b,n,o])
// D rows = o (4 consecutive per lane -> f16x4 stores), cols = b.
// Tile: (64 o) x (FN*32 b). grid (O/64, Bsz/(FN*32), Nn).
// ---------------------------------------------------------------------------
template <int FN>
__global__ __launch_bounds__(256) void gemm_mfma(
    const f16* __restrict__ Act, const float* __restrict__ Act32, int Ka,
    const f16* __restrict__ W, size_t wstride,
    const float* __restrict__ bias, int bstride,
    const f16* __restrict__ base16,
    f16* __restrict__ Y, int O)
{
    const int BN = FN * 32;
    const int n  = blockIdx.z;
    const int o0 = blockIdx.x * 64;
    const int b0 = blockIdx.y * BN;
    const int tid  = threadIdx.x;
    const int wave = tid >> 6, lane = tid & 63;
    const int wm = (wave >> 1) * 32;        // wave o offset
    const int wn = (wave & 1) * FN * 16;    // wave b offset
    const int m16 = lane & 15, quad = lane >> 4;

    __shared__ __attribute__((aligned(16))) f16 sW[64][72];
    __shared__ __attribute__((aligned(16))) f16 sB[BN][72];

    const f16* Wn = W + (size_t)n * wstride;
    f32x4 acc[2][FN] = {};
    const int r = tid >> 3, cc = (tid & 7) * 8;

    for (int k0 = 0; k0 < Ka; k0 += 64) {
        for (int row = r; row < 64; row += 32)
            *(f16x8*)&sW[row][cc] = *(const f16x8*)&Wn[(size_t)(o0 + row) * Ka + k0 + cc];
        if (Act) {
            for (int row = r; row < BN; row += 32)
                *(f16x8*)&sB[row][cc] = *(const f16x8*)&Act[((size_t)(b0 + row) * Nn + n) * Ka + k0 + cc];
        } else {
            for (int row = r; row < BN; row += 32) {
                const float* src = &Act32[((size_t)(b0 + row) * Nn + n) * Ka + k0 + cc];
                f16x8 v;
#pragma unroll
                for (int u = 0; u < 8; u++) v[u] = (f16)src[u];
                *(f16x8*)&sB[row][cc] = v;
            }
        }
        __syncthreads();
#pragma unroll
        for (int kk = 0; kk < 64; kk += 32) {
            f16x8 af[2], bf[FN];
#pragma unroll
            for (int i = 0; i < 2; i++)
                af[i] = *(const f16x8*)&sW[wm + i * 16 + m16][kk + quad * 8];
#pragma unroll
            for (int j = 0; j < FN; j++)
                bf[j] = *(const f16x8*)&sB[wn + j * 16 + m16][kk + quad * 8];
#pragma unroll
            for (int i = 0; i < 2; i++)
#pragma unroll
                for (int j = 0; j < FN; j++)
                    acc[i][j] = __builtin_amdgcn_mfma_f32_16x16x32_f16(af[i], bf[j], acc[i][j], 0, 0, 0);
        }
        __syncthreads();
    }
#pragma unroll
    for (int i = 0; i < 2; i++) {
        const int orow = o0 + wm + i * 16 + quad * 4;
        float4 bv = make_float4(0.f, 0.f, 0.f, 0.f);
        if (bias) bv = *(const float4*)&bias[(size_t)n * bstride + orow];
#pragma unroll
        for (int j = 0; j < FN; j++) {
            const int bcol = b0 + wn + j * 16 + m16;
            size_t yi = ((size_t)bcol * Nn + n) * (size_t)O + orow;
            float v0 = acc[i][j][0] + bv.x;
            float v1 = acc[i][j][1] + bv.y;
            float v2 = acc[i][j][2] + bv.z;
            float v3 = acc[i][j][3] + bv.w;
            if (base16) {
                f16x4 bb = *(const f16x4*)&base16[yi];
                v0 += (float)bb[0]; v1 += (float)bb[1];
                v2 += (float)bb[2]; v3 += (float)bb[3];
            }
            f16x4 o4; o4[0] = (f16)v0; o4[1] = (f16)v1; o4[2] = (f16)v2; o4[3] = (f16)v3;
            *(f16x4*)&Y[yi] = o4;
        }
    }
}

// ---------------------------------------------------------------------------
// Weight prep: Wz (24,512,64)=Wx0[:,:64,:]^T ; Wt0 (24,512,192)=[x8|Wh0|0]^T
// (t=0 only) ; W2ext (24,1024,256)=[[Wx1|Wh1] ; [Wh0|0]]^T ; W8 (24,8,512)=Wx0[64:72]
// ---------------------------------------------------------------------------
__global__ __launch_bounds__(256) void prep_w01(
    const float* __restrict__ Wx0, const float* __restrict__ Wh0,
    const float* __restrict__ Wx1, const float* __restrict__ Wh1,
    f16* __restrict__ Wz, f16* __restrict__ Wt0, f16* __restrict__ W2ext,
    f16* __restrict__ W8)
{
    size_t idx = (size_t)blockIdx.x * 256 + threadIdx.x;
    const size_t nz = (size_t)Nn * 512 * 64;        // 786432
    const size_t n0 = (size_t)Nn * 512 * 192;       // 2359296
    const size_t n2 = (size_t)Nn * 1024 * 256;      // 6291456
    const size_t n8 = (size_t)Nn * 8 * 512;         // 98304
    if (idx < nz) {
        int k = idx & 63; int o = (idx >> 6) & 511; int n = (int)(idx >> 15);
        Wz[idx] = (f16)Wx0[((size_t)n * 72 + k) * 512 + o];
    } else if (idx < nz + n0) {
        size_t i2 = idx - nz;
        int k = (int)(i2 % 192);
        size_t no = i2 / 192;
        int o = (int)(no & 511); int n = (int)(no >> 9);
        float v = 0.f;
        if (k < 8) v = Wx0[((size_t)n * 72 + 64 + k) * 512 + o];
        else if (k < 136) v = Wh0[((size_t)n * 128 + (k - 8)) * 512 + o];
        Wt0[i2] = (f16)v;
    } else if (idx < nz + n0 + n2) {
        size_t i3 = idx - nz - n0;
        int k = (int)(i3 & 255);
        size_t no = i3 >> 8;
        int o = (int)(no & 1023); int n = (int)(no >> 10);
        float v;
        if (o < 512) v = (k < 128) ? Wx1[((size_t)n * 128 + k) * 512 + o]
                                   : Wh1[((size_t)n * 128 + (k - 128)) * 512 + o];
        else         v = (k < 128) ? Wh0[((size_t)n * 128 + k) * 512 + (o - 512)] : 0.f;
        W2ext[i3] = (f16)v;
    } else if (idx < nz + n0 + n2 + n8) {
        size_t i4 = idx - nz - n0 - n2;
        int o = (int)(i4 & 511);
        size_t ko = i4 >> 9;
        int k = (int)(ko & 7); int n = (int)(ko >> 3);
        W8[i4] = (f16)Wx0[((size_t)n * 72 + 64 + k) * 512 + o];
    }
}

// Wtf (24,256,128): o<128 -> fcW^T, else fc2W^T
__global__ __launch_bounds__(256) void prep_wf(
    const float* __restrict__ fcW, const float* __restrict__ fc2W,
    f16* __restrict__ Wtf)
{
    size_t idx = (size_t)blockIdx.x * 256 + threadIdx.x;
    if (idx >= (size_t)Nn * 256 * 128) return;
    int k = (int)(idx & 127);
    size_t no = idx >> 7;
    int o = (int)(no & 255); int n = (int)(no >> 8);
    float v = (o < 128) ? fcW[((size_t)n * 128 + k) * 128 + o]
                        : fc2W[((size_t)n * 128 + k) * 128 + (o - 128)];
    Wtf[idx] = (f16)v;
}

// Wti (256,256)=[ih1W|ih2W]^T ; bi (256) ; bcat (24,256) ; bcat2 (24,1024)=[b1|0]
__global__ __launch_bounds__(256) void prep_wi(
    const float* __restrict__ ih1W, const float* __restrict__ ih2W,
    const float* __restrict__ ih1b, const float* __restrict__ ih2b,
    const float* __restrict__ fcb, const float* __restrict__ fc2b,
    const float* __restrict__ b1,
    f16* __restrict__ Wti, float* __restrict__ bi, float* __restrict__ bcat,
    float* __restrict__ bcat2)
{
    int idx = blockIdx.x * 256 + threadIdx.x;   // 65536
    int k = idx & 255, o = idx >> 8;
    Wti[idx] = (f16)((o < 128) ? ih1W[(size_t)k * 128 + o] : ih2W[(size_t)k * 128 + (o - 128)]);
    if (idx < 256) bi[idx] = (idx < 128) ? ih1b[idx] : ih2b[idx - 128];
    if (idx < Nn * 256) {
        int n = idx >> 8, oo = idx & 255;
        bcat[idx] = (oo < 128) ? fcb[n * 128 + oo] : fc2b[n * 128 + (oo - 128)];
    }
    if (idx < Nn * 1024) {
        int n = idx >> 10, oo = idx & 1023;
        bcat2[idx] = (oo < 512) ? b1[n * 512 + oo] : 0.f;
    }
}

// xi2[b,n,0:8)=x, [136:192)=0 ([8:136) = h0, filled by mix_init); ls=x[:4]
__global__ __launch_bounds__(256) void init_xi(
    const float* __restrict__ x, f16* __restrict__ xi2, float* __restrict__ ls)
{
    size_t idx = (size_t)blockIdx.x * 256 + threadIdx.x;
    const size_t total = (size_t)Bsz * Nn * 192;
    if (idx < total) {
        size_t bn = idx / 192;
        int k = (int)(idx - bn * 192);
        if (k < 8) xi2[idx] = (f16)x[bn * 8 + k];
        else if (k >= 136) xi2[idx] = (f16)0.f;
    }
    if (idx < (size_t)Bsz * Nn * 4) {
        size_t bn = idx >> 2;
        ls[idx] = x[bn * 8 + (idx & 3)];
    }
}

// ---------------------------------------------------------------------------
// Init mix: Yhc (B,N,256) f16 = [h-pre|c-pre]; h0 -> xi2[8:136), l2cat both
// halves; c0 -> c1, c2.
// ---------------------------------------------------------------------------
__global__ __launch_bounds__(256) void mix_init(
    const f16* __restrict__ Yhc, const float* __restrict__ G,
    f16* __restrict__ xi2, f16* __restrict__ l2cat,
    float* __restrict__ c1, float* __restrict__ c2)
{
    const int b = blockIdx.x;
    const int tid = threadIdx.x;
    __shared__ float sY[6144], sG[576];
    for (int i = tid; i < 576; i += 256) sG[i] = G[i];
    for (int v = tid; v < 768; v += 256) {
        int c8 = (v & 31) * 8, n = v >> 5;
        f16x8 t = *(const f16x8*)&Yhc[((size_t)b * Nn + n) * 256 + c8];
        float* d = &sY[n * 256 + c8];
#pragma unroll
        for (int u = 0; u < 8; u++) d[u] = (float)t[u];
    }
    __syncthreads();
    for (int w = tid; w < 3072; w += 256) {
        int o = w & 127, m = w >> 7;
        float ah = 0.f, ac = 0.f;
#pragma unroll
        for (int n = 0; n < 24; n++) {
            float g = sG[m * 24 + n];
            ah += g * sY[n * 256 + o];
            ac += g * sY[n * 256 + 128 + o];
        }
        size_t row = (size_t)b * Nn + m;
        f16 hf = (f16)ah;
        xi2[row * 192 + 8 + o] = hf;
        l2cat[row * 256 + o] = hf;
        l2cat[row * 256 + 128 + o] = hf;
        c1[row * 128 + o] = ac;
        c2[row * 128 + o] = ac;
    }
}

// ---------------------------------------------------------------------------
// G-mix + LSTM pointwise, one block per batch element.
// Ypre row stride = ystride (512 for ypA, 1024 for ypB; gates in [0,512)).
// h -> dstA (raw f16, stride strideA); if dstB: tanh(h) -> dstB.
// ---------------------------------------------------------------------------
__global__ __launch_bounds__(256) void mixlstm_b(
    const f16* __restrict__ Ypre, int ystride, const float* __restrict__ G,
    float* __restrict__ c,
    f16* __restrict__ dstA, int strideA,
    f16* __restrict__ dstB, int strideB)
{
    const int b = blockIdx.x;
    const int tid = threadIdx.x;
    __shared__ __attribute__((aligned(16))) f16 sY[12288];  // 24 x 512
    __shared__ float sG[576];
    for (int i = tid; i < 576; i += 256) sG[i] = G[i];
    for (int i = tid; i < 1536; i += 256) {
        int n = i >> 6, c8 = (i & 63) * 8;
        *(f16x8*)&sY[n * 512 + c8] = *(const f16x8*)&Ypre[((size_t)b * Nn + n) * ystride + c8];
    }
    __syncthreads();
    for (int w = tid; w < 768; w += 256) {
        const int m = w >> 5, j4 = (w & 31) * 4;
        float gi[4] = {}, gf[4] = {}, gg[4] = {}, go[4] = {};
        const float* gr = &sG[m * 24];
#pragma unroll
        for (int n = 0; n < 24; n++) {
            float g = gr[n];
            const f16* yn = &sY[n * 512];
            f16x4 vi = *(const f16x4*)&yn[j4];
            f16x4 vf = *(const f16x4*)&yn[128 + j4];
            f16x4 vg = *(const f16x4*)&yn[256 + j4];
            f16x4 vo = *(const f16x4*)&yn[384 + j4];
#pragma unroll
            for (int u = 0; u < 4; u++) {
                gi[u] += g * (float)vi[u];
                gf[u] += g * (float)vf[u];
                gg[u] += g * (float)vg[u];
                go[u] += g * (float)vo[u];
            }
        }
        const size_t row = (size_t)b * Nn + m;
        float cv[4];
        *(float4*)cv = *(const float4*)&c[row * 128 + j4];
        f16x4 ha, hb;
#pragma unroll
        for (int u = 0; u < 4; u++) {
            float si = 1.f / (1.f + expf(-gi[u]));
            float sf = 1.f / (1.f + expf(-gf[u]));
            float so = 1.f / (1.f + expf(-go[u]));
            float cn = sf * cv[u] + si * tanhf(gg[u]);
            cv[u] = cn;
            float h = so * tanhf(cn);
            ha[u] = (f16)h;
            hb[u] = (f16)tanhf(h);
        }
        *(float4*)&c[row * 128 + j4] = *(float4*)cv;
        *(f16x4*)&dstA[row * strideA + j4] = ha;
        if (dstB) *(f16x4*)&dstB[row * strideB + j4] = hb;
    }
}

// ---------------------------------------------------------------------------
// finstep+: fc-mix + tanh, heads, second mix, quaternion, outputs, AND
// complete next step's gates1: ypA = partial1 (ypB[512:1024)) + base1 + v8·W8.
// One block per batch element.
// ---------------------------------------------------------------------------
__global__ __launch_bounds__(256) void finstep(
    const f16* __restrict__ p, const f16* __restrict__ ypB,
    const f16* __restrict__ base1, const f16* __restrict__ W8,
    const float* __restrict__ G,
    const float* __restrict__ locW, const float* __restrict__ locb,
    const float* __restrict__ lzW, const float* __restrict__ lzb,
    float* __restrict__ ls, f16* __restrict__ ypA,
    float* __restrict__ out, int t)
{
    const int b = blockIdx.x;
    const int tid = threadIdx.x;
    __shared__ __attribute__((aligned(16))) f16 sP[6144];
    __shared__ __attribute__((aligned(16))) f16 sY1[3072], sY2[3072];
    __shared__ float sG[576];
    __shared__ float sLp[24][3], sZp[24][4], sL3[24][3], sZ3[24][4];
    __shared__ float sV8[24][8];
    for (int i = tid; i < 576; i += 256) sG[i] = G[i];
    for (int i = tid; i < 768; i += 256) {
        int n = i >> 5, c8 = (i & 31) * 8;
        *(f16x8*)&sP[n * 256 + c8] = *(const f16x8*)&p[((size_t)b * Nn + n) * 256 + c8];
    }
    __syncthreads();
    for (int w = tid; w < 768; w += 256) {
        const int m = w >> 5, o4 = (w & 31) * 4;
        float a1[4] = {}, a2[4] = {};
        const float* gr = &sG[m * 24];
#pragma unroll
        for (int n = 0; n < 24; n++) {
            float g = gr[n];
            f16x4 p1 = *(const f16x4*)&sP[n * 256 + o4];
            f16x4 p2 = *(const f16x4*)&sP[n * 256 + 128 + o4];
#pragma unroll
            for (int u = 0; u < 4; u++) { a1[u] += g * (float)p1[u]; a2[u] += g * (float)p2[u]; }
        }
        f16x4 y1, y2;
#pragma unroll
        for (int u = 0; u < 4; u++) { y1[u] = (f16)tanhf(a1[u]); y2[u] = (f16)tanhf(a2[u]); }
        *(f16x4*)&sY1[m * 128 + o4] = y1;
        *(f16x4*)&sY2[m * 128 + o4] = y2;
    }
    __syncthreads();
    if (tid < 72) {
        int m = tid / 3, j = tid - m * 3;
        float s = locb[j];
        for (int o = 0; o < 128; o++) s += (float)sY1[m * 128 + o] * locW[o * 3 + j];
        sLp[m][j] = s;
    } else if (tid < 168) {
        int w2 = tid - 72; int m = w2 >> 2, j = w2 & 3;
        float s = lzb[j];
        for (int o = 0; o < 128; o++) s += (float)sY2[m * 128 + o] * lzW[o * 4 + j];
        sZp[m][j] = s;
    }
    __syncthreads();
    if (tid < 72) {
        int m = tid / 3, j = tid - m * 3;
        float s = 0.f;
#pragma unroll
        for (int n = 0; n < 24; n++) s += sG[m * 24 + n] * sLp[n][j];
        sL3[m][j] = s;
    } else if (tid < 168) {
        int w2 = tid - 72; int m = w2 >> 2, j = w2 & 3;
        float s = 0.f;
#pragma unroll
        for (int n = 0; n < 24; n++) s += sG[m * 24 + n] * sZp[n][j];
        sZ3[m][j] = s;
    }
    __syncthreads();
    if (tid < 24) {
        const int m = tid;
        float xx = sL3[m][0], xy = sL3[m][1], xz = sL3[m][2];
        float r = rsqrtf(1.f + xx * xx + xy * xy + xz * xz);
        float dw = r, dx = xx * r, dy = xy * r, dz = xz * r;
        size_t li = ((size_t)b * Nn + m) * 4;
        float qw = ls[li], qx = ls[li + 1], qy = ls[li + 2], qz = ls[li + 3];
        float lw = qw * dw - qx * dx - qy * dy - qz * dz;
        float lx = qw * dx + qx * dw + qy * dz - qz * dy;
        float ly = qw * dy - qx * dz + qy * dw + qz * dx;
        float lz = qw * dz + qx * dy - qy * dx + qz * dw;
        size_t oi = (((size_t)b * Tt + t) * Nn + m) * 4;
        out[oi + 0] = lw; out[oi + 1] = lx; out[oi + 2] = ly; out[oi + 3] = lz;
        size_t zi = (size_t)Bsz * Tt * Nn * 4 + oi;
        out[zi + 0] = sZ3[m][0]; out[zi + 1] = sZ3[m][1];
        out[zi + 2] = sZ3[m][2]; out[zi + 3] = sZ3[m][3];
        ls[li] = lw; ls[li + 1] = lx; ls[li + 2] = ly; ls[li + 3] = lz;
        sV8[m][0] = lw; sV8[m][1] = lx; sV8[m][2] = ly; sV8[m][3] = lz;
        sV8[m][4] = dw; sV8[m][5] = dx; sV8[m][6] = dy; sV8[m][7] = dz;
    }
    __syncthreads();
    // ---- complete gates1(t+1): ypA = partial1 + base1 + v8 . W8 ----
    for (int g = tid; g < 1536; g += 256) {
        const int n = g >> 6, o8 = (g & 63) * 8;
        const size_t rowb = (size_t)b * Nn + n;
        f16x8 pp = *(const f16x8*)&ypB[rowb * 1024 + 512 + o8];
        f16x8 bb = *(const f16x8*)&base1[rowb * 512 + o8];
        float acc[8];
#pragma unroll
        for (int u = 0; u < 8; u++) acc[u] = (float)pp[u] + (float)bb[u];
#pragma unroll
        for (int k = 0; k < 8; k++) {
            float v = sV8[n][k];
            f16x8 ww = *(const f16x8*)&W8[((size_t)n * 8 + k) * 512 + o8];
#pragma unroll
            for (int u = 0; u < 8; u++) acc[u] += v * (float)ww[u];
        }
        f16x8 oo;
#pragma unroll
        for (int u = 0; u < 8; u++) oo[u] = (f16)acc[u];
        *(f16x8*)&ypA[rowb * 512 + o8] = oo;
    }
}

extern "C" void kernel_launch(void* const* d_in, const int* in_sizes, int n_in,
                              void* d_out, int out_size, void* d_ws, size_t ws_size,
                              hipStream_t stream)
{
    const float* x    = (const float*)d_in[0];
    const float* enc  = (const float*)d_in[1];
    const float* z    = (const float*)d_in[2];
    const float* G    = (const float*)d_in[4];
    const float* Wx0  = (const float*)d_in[5];
    const float* Wh0  = (const float*)d_in[6];
    const float* b0i  = (const float*)d_in[7];
    const float* Wx1  = (const float*)d_in[8];
    const float* Wh1  = (const float*)d_in[9];
    const float* b1i  = (const float*)d_in[10];
    const float* fcW  = (const float*)d_in[11];
    const float* fcb  = (const float*)d_in[12];
    const float* fc2W = (const float*)d_in[13];
    const float* fc2b = (const float*)d_in[14];
    const float* ih1W = (const float*)d_in[15];
    const float* ih1b = (const float*)d_in[16];
    const float* ih2W = (const float*)d_in[17];
    const float* ih2b = (const float*)d_in[18];
    const float* locW = (const float*)d_in[19];
    const float* locb = (const float*)d_in[20];
    const float* lzW  = (const float*)d_in[21];
    const float* lzb  = (const float*)d_in[22];
    float* out = (float*)d_out;

    const size_t BN = (size_t)Bsz * Nn;
    char* wp = (char*)d_ws;
    size_t off = 0;
    auto carve = [&](size_t bytes) -> char* {
        char* pc = wp + off;
        off += (bytes + 255) & ~(size_t)255;
        return pc;
    };
    f16*   Wz     = (f16*)carve((size_t)Nn * 512 * 64 * 2);
    f16*   Wt0    = (f16*)carve((size_t)Nn * 512 * 192 * 2);
    f16*   W2ext  = (f16*)carve((size_t)Nn * 1024 * 256 * 2);
    f16*   W8     = (f16*)carve((size_t)Nn * 8 * 512 * 2);
    f16*   Wtf    = (f16*)carve((size_t)Nn * 256 * 128 * 2);
    f16*   Wti    = (f16*)carve((size_t)256 * 256 * 2);
    float* bcat   = (float*)carve((size_t)Nn * 256 * 4);
    float* bcat2  = (float*)carve((size_t)Nn * 1024 * 4);
    float* bi     = (float*)carve(256 * 4);
    f16*   base1  = (f16*)carve(BN * 512 * 2);
    f16*   xi2    = (f16*)carve(BN * 192 * 2);
    f16*   l2cat  = (f16*)carve(BN * 256 * 2);
    f16*   yib    = (f16*)carve(BN * 128 * 2);
    float* c1     = (float*)carve(BN * 128 * 4);
    float* c2     = (float*)carve(BN * 128 * 4);
    float* ls     = (float*)carve(BN * 4 * 4);
    f16*   ypA    = (f16*)carve(BN * 512 * 2);
    f16*   ypB    = (f16*)carve(BN * 1024 * 2);
    f16*   yp0    = (f16*)carve(BN * 256 * 2);
    f16*   pbuf   = (f16*)carve(BN * 256 * 2);

    // ---- one-time prep ----
    prep_w01<<<37248, 256, 0, stream>>>(Wx0, Wh0, Wx1, Wh1, Wz, Wt0, W2ext, W8);
    prep_wf<<<3072, 256, 0, stream>>>(fcW, fc2W, Wtf);
    prep_wi<<<256, 256, 0, stream>>>(ih1W, ih2W, ih1b, ih2b, fcb, fc2b, b1i,
                                     Wti, bi, bcat, bcat2);
    init_xi<<<9216, 256, 0, stream>>>(x, xi2, ls);

    // base1 = z.Wz + b0 (constant over all steps)
    gemm_mfma<4><<<dim3(8, 4, 24), 256, 0, stream>>>(
        nullptr, z, 64, Wz, (size_t)512 * 64, b0i, 512, nullptr, base1, 512);
    // init states: [h0|c0]pre from enc, then mix into xi2/l2cat/c1/c2
    gemm_mfma<4><<<dim3(4, 4, 24), 256, 0, stream>>>(
        nullptr, enc, 256, Wti, 0, bi, 0, nullptr, yp0, 256);
    mix_init<<<512, 256, 0, stream>>>(yp0, G, xi2, l2cat, c1, c2);
    // gates1(0) = xi2.Wt0 + base1
    gemm_mfma<4><<<dim3(8, 4, 24), 256, 0, stream>>>(
        xi2, nullptr, 192, Wt0, (size_t)512 * 192, nullptr, 0, base1, ypA, 512);

    // ---- T sequential steps: 5 kernels each ----
    for (int t = 0; t < Tt; t++) {
        mixlstm_b<<<512, 256, 0, stream>>>(ypA, 512, G, c1, l2cat, 256, nullptr, 0);
        gemm_mfma<8><<<dim3(16, 2, 24), 256, 0, stream>>>(
            l2cat, nullptr, 256, W2ext, (size_t)1024 * 256, bcat2, 1024, nullptr, ypB, 1024);
        mixlstm_b<<<512, 256, 0, stream>>>(ypB, 1024, G, c2, l2cat + 128, 256, yib, 128);
        gemm_mfma<4><<<dim3(4, 4, 24), 256, 0, stream>>>(
            yib, nullptr, 128, Wtf, (size_t)256 * 128, bcat, 256, nullptr, pbuf, 256);
        finstep<<<512, 256, 0, stream>>>(pbuf, ypB, base1, W8, G, locW, locb, lzW, lzb,
                                         ls, ypA, out, t);
    }
}